// Round 9
// baseline (342.310 us; speedup 1.0000x reference)
//
#include <hip/hip_runtime.h>
#include <hip/hip_bf16.h>

#define N_NODE  50000
#define N_PAD   50048   // 391 * 128
#define N_GRAPH 1024
#define DD      512
// 128-tile bf16 core (ff):
#define BK      64
#define NT      (DD / BK)   // 8 K-steps
// 256-tile fp8 core (jsd):
#define BKT8    64
#define NKT8    8           // 512 / 64

typedef __attribute__((ext_vector_type(8))) short bf16x8;
typedef __attribute__((ext_vector_type(4))) float f32x4;

__device__ __forceinline__ unsigned short f2bf(float f) {
  unsigned int u = __builtin_bit_cast(unsigned int, f);
  return (unsigned short)((u + 0x7FFFu + ((u >> 16) & 1u)) >> 16);  // RTN-even
}

// manual fp32 -> fp8 e4m3fn, RNE (no builtin dependency)
__device__ __forceinline__ unsigned char f2fp8(float f) {
  unsigned int u = __builtin_bit_cast(unsigned int, f);
  unsigned char s = (unsigned char)((u >> 24) & 0x80u);
  float a = __builtin_bit_cast(float, u & 0x7fffffffu);
  if (a >= 448.f) return (unsigned char)(s | 0x7E);
  if (a < 0.015625f) {                       // < 2^-6 -> subnormal (ulp 2^-9)
    int q = (int)rintf(a * 512.f);           // 0..8; 8 -> 0x08 == 2^-6 normal
    return (unsigned char)(s | (unsigned char)q);
  }
  int exp = (int)((u >> 23) & 0xffu) - 127;  // in [-6, 8]
  unsigned int man = u & 0x7fffffu;
  unsigned int keep = man >> 20;
  unsigned int rest = man & 0xfffffu;
  unsigned int rb = (rest > 0x80000u || (rest == 0x80000u && (keep & 1u))) ? 1u : 0u;
  unsigned int m3 = keep + rb;
  int e4 = exp + 7;
  if (m3 == 8u) { m3 = 0u; e4 += 1; }
  if (e4 >= 16 || (e4 == 15 && m3 == 7u)) return (unsigned char)(s | 0x7E);
  return (unsigned char)(s | (unsigned char)((e4 << 3) | (int)m3));
}

__device__ __forceinline__ void gload16(const void* g, void* l) {
  __builtin_amdgcn_global_load_lds(
      (const __attribute__((address_space(1))) unsigned int*)g,
      (__attribute__((address_space(3))) unsigned int*)l, 16, 0, 0);
}

// T1: bijective XCD-chunk remap (m204 variant)
__device__ __forceinline__ int xcd_remap(int bid, int nwg) {
  int xcd = bid & 7;
  int local = bid >> 3;
  int q = nwg >> 3, r = nwg & 7;
  int base = (xcd < r) ? xcd * (q + 1) : r * (q + 1) + (xcd - r) * q;
  return base + local;
}

// ---- cast kernels -----------------------------------------------------------

__global__ void cast_pad_kernel(const float* __restrict__ src,
                                unsigned short* __restrict__ dst,
                                int srcRows, int dstRows) {
  long long base = ((long long)blockIdx.x * blockDim.x + threadIdx.x) * 8;
  if (base >= (long long)dstRows * DD) return;
  int row = (int)(base >> 9);
  bf16x8 o;
  if (row < srcRows) {
    float4 x0 = reinterpret_cast<const float4*>(src + base)[0];
    float4 x1 = reinterpret_cast<const float4*>(src + base)[1];
    o[0] = (short)f2bf(x0.x); o[1] = (short)f2bf(x0.y);
    o[2] = (short)f2bf(x0.z); o[3] = (short)f2bf(x0.w);
    o[4] = (short)f2bf(x1.x); o[5] = (short)f2bf(x1.y);
    o[6] = (short)f2bf(x1.z); o[7] = (short)f2bf(x1.w);
  } else {
    for (int i = 0; i < 8; ++i) o[i] = 0;
  }
  *reinterpret_cast<bf16x8*>(dst + base) = o;
}

struct WPtrs { const float* p[8]; };

__global__ void cast_w_kernel(WPtrs ps, unsigned short* __restrict__ dst) {
  long long base = ((long long)blockIdx.x * blockDim.x + threadIdx.x) * 8;
  int mat = (int)(base >> 18);
  int off = (int)(base & 262143LL);
  const float* s = ps.p[mat] + off;
  float4 x0 = reinterpret_cast<const float4*>(s)[0];
  float4 x1 = reinterpret_cast<const float4*>(s)[1];
  bf16x8 o;
  o[0] = (short)f2bf(x0.x); o[1] = (short)f2bf(x0.y);
  o[2] = (short)f2bf(x0.z); o[3] = (short)f2bf(x0.w);
  o[4] = (short)f2bf(x1.x); o[5] = (short)f2bf(x1.y);
  o[6] = (short)f2bf(x1.z); o[7] = (short)f2bf(x1.w);
  *reinterpret_cast<bf16x8*>(dst + base) = o;
}

__global__ void zeropad8_kernel(unsigned char* __restrict__ H) {
  long long i = (long long)blockIdx.x * blockDim.x + threadIdx.x;
  long long base = (long long)N_NODE * DD + i * 16;
  if (base < (long long)N_PAD * DD) {
    int4 z = {0, 0, 0, 0};
    *reinterpret_cast<int4*>(H + base) = z;
  }
}

// ============================================================================
// ff side: R2's measured-good 128x128 bf16 core (depth-1 prefetch, BK=64)
// ============================================================================

__device__ __forceinline__ void stage_tile(const unsigned short* __restrict__ G,
                                           long long rowBase, int kcol,
                                           unsigned short* lds, int tid) {
  const int rr   = tid >> 3;
  const int csrc = (tid & 7) ^ (rr & 7);
  const unsigned short* src = G + (rowBase + rr) * DD + kcol + csrc * 8;
  unsigned short* dstbase = lds + ((tid >> 6) << 9);
  #pragma unroll
  for (int r = 0; r < 4; ++r)
    gload16(src + (long long)r * 32 * DD, dstbase + r * 2048);
}

__device__ __forceinline__ void gemm_core64(
    const unsigned short* __restrict__ A, const unsigned short* __restrict__ B,
    unsigned short* As, unsigned short* Bs,
    long long brow, long long bcol, int wr, int wc, int lane, int tid,
    f32x4 acc[4][4]) {
  const int rA = wr * 64 + (lane & 15);
  const int rB = wc * 64 + (lane & 15);
  const int c16b = lane >> 4;

  stage_tile(A, brow, 0, As, tid);
  stage_tile(B, bcol, 0, Bs, tid);
  __syncthreads();

  for (int kt = 0; kt < NT; ++kt) {
    const int cur = kt & 1;
    if (kt + 1 < NT) {
      stage_tile(A, brow, (kt + 1) * BK, As + (cur ^ 1) * 8192, tid);
      stage_tile(B, bcol, (kt + 1) * BK, Bs + (cur ^ 1) * 8192, tid);
    }
    const unsigned short* as = As + cur * 8192;
    const unsigned short* bs = Bs + cur * 8192;
    #pragma unroll
    for (int kk = 0; kk < 2; ++kk) {
      bf16x8 a[4], b[4];
      #pragma unroll
      for (int m = 0; m < 4; ++m) {
        const int row = rA + m * 16;
        const int c16 = (c16b + kk * 4) ^ (row & 7);
        a[m] = *reinterpret_cast<const bf16x8*>(as + row * 64 + c16 * 8);
      }
      #pragma unroll
      for (int n = 0; n < 4; ++n) {
        const int row = rB + n * 16;
        const int c16 = (c16b + kk * 4) ^ (row & 7);
        b[n] = *reinterpret_cast<const bf16x8*>(bs + row * 64 + c16 * 8);
      }
      #pragma unroll
      for (int m = 0; m < 4; ++m)
        #pragma unroll
        for (int n = 0; n < 4; ++n)
          acc[m][n] = __builtin_amdgcn_mfma_f32_16x16x32_bf16(a[m], b[n], acc[m][n], 0, 0, 0);
    }
    __syncthreads();
  }
}

// ---- FF GEMM: C = relu(A@W^T + bias); DUAL: writes fp8 (relu(h2W2+b2)+xWs+bs)

template <int DUAL>
__global__ __launch_bounds__(256, 2) void gemm_ff_kernel(
    const unsigned short* __restrict__ Al, const unsigned short* __restrict__ Wl,
    const float* __restrict__ biasl, unsigned short* __restrict__ Cl,
    const unsigned short* __restrict__ A2l, const unsigned short* __restrict__ W2l,
    const float* __restrict__ bias2l, int nwgL,
    const unsigned short* __restrict__ Ag, const unsigned short* __restrict__ Wg,
    const float* __restrict__ biasg, unsigned short* __restrict__ Cg,
    const unsigned short* __restrict__ A2g, const unsigned short* __restrict__ W2g,
    const float* __restrict__ bias2g) {
  __shared__ unsigned short As[2 * 8192];
  __shared__ unsigned short Bs[2 * 8192];
  const int tid = threadIdx.x;
  const int lane = tid & 63, wid = tid >> 6;
  const int wr = wid >> 1, wc = wid & 1;

  int tile = xcd_remap(blockIdx.x, gridDim.x);
  const unsigned short *A, *W, *A2, *W2;
  const float *bias, *bias2;
  unsigned short* C;
  if (tile < nwgL) {
    A = Al; W = Wl; bias = biasl; C = Cl; A2 = A2l; W2 = W2l; bias2 = bias2l;
  } else {
    tile -= nwgL;
    A = Ag; W = Wg; bias = biasg; C = Cg; A2 = A2g; W2 = W2g; bias2 = bias2g;
  }
  const long long brow = (long long)(tile >> 2) * 128;
  const long long bcol = (long long)(tile & 3) * 128;

  f32x4 zero = {0.f, 0.f, 0.f, 0.f};
  f32x4 acc[4][4];
  #pragma unroll
  for (int m = 0; m < 4; ++m)
    #pragma unroll
    for (int n = 0; n < 4; ++n) acc[m][n] = zero;

  gemm_core64(A, W, As, Bs, brow, bcol, wr, wc, lane, tid, acc);

  float bv[4];
  #pragma unroll
  for (int n = 0; n < 4; ++n) bv[n] = bias[bcol + wc * 64 + n * 16 + (lane & 15)];

  if constexpr (DUAL) {
    float r[4][4][4];
    #pragma unroll
    for (int m = 0; m < 4; ++m)
      #pragma unroll
      for (int n = 0; n < 4; ++n)
        #pragma unroll
        for (int j = 0; j < 4; ++j)
          r[m][n][j] = fmaxf(acc[m][n][j] + bv[n], 0.f);
    #pragma unroll
    for (int m = 0; m < 4; ++m)
      #pragma unroll
      for (int n = 0; n < 4; ++n) acc[m][n] = zero;

    gemm_core64(A2, W2, As, Bs, brow, bcol, wr, wc, lane, tid, acc);

    float b2[4];
    #pragma unroll
    for (int n = 0; n < 4; ++n) b2[n] = bias2[bcol + wc * 64 + n * 16 + (lane & 15)];

    unsigned char* C8 = (unsigned char*)C;   // DUAL output is fp8 e4m3 (enc)
    #pragma unroll
    for (int m = 0; m < 4; ++m) {
      const long long row = brow + wr * 64 + m * 16 + (lane >> 4) * 4;
      #pragma unroll
      for (int j = 0; j < 4; ++j)
        #pragma unroll
        for (int n = 0; n < 4; ++n) {
          const long long col = bcol + wc * 64 + n * 16 + (lane & 15);
          float v = r[m][n][j] + acc[m][n][j] + b2[n];
          C8[(row + j) * DD + col] = f2fp8(v);
        }
    }
  } else {
    #pragma unroll
    for (int m = 0; m < 4; ++m) {
      const long long row = brow + wr * 64 + m * 16 + (lane >> 4) * 4;
      #pragma unroll
      for (int j = 0; j < 4; ++j)
        #pragma unroll
        for (int n = 0; n < 4; ++n) {
          const long long col = bcol + wc * 64 + n * 16 + (lane & 15);
          float v = fmaxf(acc[m][n][j] + bv[n], 0.f);
          C[(row + j) * DD + col] = f2bf(v);
        }
    }
  }
}

// ============================================================================
// jsd side: 256x256 fp8 core — R4's proven 4-slot/counted-vmcnt skeleton,
// re-scaled to fp8: BKT=64 fp8 = 64B rows (same byte layout, same swizzle),
// NKT 16->8 (half the barriers/stage-issues/ds-bytes), 2x32 MFMA per step.
// ============================================================================

struct StageSrc8 { const unsigned char *a0, *a1, *b0, *b1; };

__device__ __forceinline__ void issue_stage8(const StageSrc8& s, int kbyte,
                                             unsigned char* sA, unsigned char* sB,
                                             int wid) {
  unsigned char* dA = sA + wid * 1024;   // wave-uniform; HW adds lane*16B
  unsigned char* dB = sB + wid * 1024;
  gload16(s.a0 + kbyte, dA);
  gload16(s.a1 + kbyte, dA + 8192);
  gload16(s.b0 + kbyte, dB);
  gload16(s.b1 + kbyte, dB + 8192);
}

__device__ __forceinline__ void gemm_core256_fp8(
    const StageSrc8& s, unsigned char* As, unsigned char* Bs,
    int wid, int rA, int rB, int off0, int off1, f32x4 acc[8][4]) {
  issue_stage8(s, 0, As, Bs, wid);
  issue_stage8(s, BKT8, As + 16384, Bs + 16384, wid);
  issue_stage8(s, 2 * BKT8, As + 32768, Bs + 32768, wid);
  #pragma unroll
  for (int t = 0; t < NKT8; ++t) {
    __builtin_amdgcn_sched_barrier(0);
    if (t < NKT8 - 2)       asm volatile("s_waitcnt vmcnt(8)" ::: "memory");
    else if (t == NKT8 - 2) asm volatile("s_waitcnt vmcnt(4)" ::: "memory");
    else                    asm volatile("s_waitcnt vmcnt(0)" ::: "memory");
    __builtin_amdgcn_s_barrier();
    __builtin_amdgcn_sched_barrier(0);
    if (t + 3 < NKT8)
      issue_stage8(s, (t + 3) * BKT8, As + ((t + 3) & 3) * 16384,
                   Bs + ((t + 3) & 3) * 16384, wid);
    const unsigned char* as = As + (t & 3) * 16384;
    const unsigned char* bs = Bs + (t & 3) * 16384;
    #pragma unroll
    for (int kk = 0; kk < 2; ++kk) {
      const int off = kk ? off1 : off0;
      long long a[8], b[4];
      #pragma unroll
      for (int m = 0; m < 8; ++m)
        a[m] = *reinterpret_cast<const long long*>(as + (rA + m * 16) * 64 + off);
      #pragma unroll
      for (int n = 0; n < 4; ++n)
        b[n] = *reinterpret_cast<const long long*>(bs + (rB + n * 16) * 64 + off);
      __builtin_amdgcn_s_setprio(1);
      #pragma unroll
      for (int m = 0; m < 8; ++m)
        #pragma unroll
        for (int n = 0; n < 4; ++n)
          acc[m][n] = __builtin_amdgcn_mfma_f32_16x16x32_fp8_fp8(a[m], b[n], acc[m][n], 0, 0, 0);
      __builtin_amdgcn_s_setprio(0);
    }
  }
}

// accum[0] = sum_diag (LN2 - softplus(-v))
// accum[1] = sum_all  (softplus(-v) + v)   (rows < N_PAD; zero rows -> ln2)
// accum[2] = sum_diag (softplus(-v) + v)

__global__ __launch_bounds__(512, 2) void gemm_jsd256(
    const unsigned char* __restrict__ A, const unsigned char* __restrict__ B,
    const int* __restrict__ batch, double* __restrict__ accum) {
  __shared__ unsigned char As[4 * 16384];
  __shared__ unsigned char Bs[4 * 16384];
  __shared__ int sbatch[256];
  __shared__ float sred[24];
  const int tid = threadIdx.x;
  const int lane = tid & 63, wid = tid >> 6;
  const int wr = wid >> 2, wc = wid & 3;

  const int tile = xcd_remap(blockIdx.x, gridDim.x);
  const long long brow = (long long)(tile >> 2) * 256;
  const long long bcol = (long long)(tile & 3) * 256;

  if (tid < 256) {
    long long gr = brow + tid;
    sbatch[tid] = (gr < N_NODE) ? batch[gr] : -1;
  }

  // staging: row rr = tid>>2, superslot (16B) p = tid&3 holds logical
  // p ^ ((rr>>1)&3); inverse-swizzle applied on the GLOBAL source (rule 21).
  const int srow = tid >> 2;
  const int csrc16 = ((tid & 3) ^ ((tid >> 3) & 3)) * 16;
  long long ra0 = brow + srow;        if (ra0 > N_PAD - 1) ra0 = N_PAD - 1;
  long long ra1 = brow + 128 + srow;  if (ra1 > N_PAD - 1) ra1 = N_PAD - 1;
  StageSrc8 s;
  s.a0 = A + ra0 * DD + csrc16;
  s.a1 = A + ra1 * DD + csrc16;
  s.b0 = B + (bcol + srow) * DD + csrc16;
  s.b1 = B + (bcol + 128 + srow) * DD + csrc16;

  const int rA = wr * 128 + (lane & 15);
  const int rB = wc * 64 + (lane & 15);
  const int qa = lane >> 4;                       // K-group 0..3
  const int sa = ((lane & 15) >> 1) & 3;          // row swizzle key (same A/B)
  // logical superslot for kk: kk*2 + (qa>>1); intra-slot half: (qa&1)*8
  const int off0 = ((((0 * 2) + (qa >> 1)) ^ sa) << 4) + ((qa & 1) << 3);
  const int off1 = ((((1 * 2) + (qa >> 1)) ^ sa) << 4) + ((qa & 1) << 3);

  f32x4 acc[8][4];
  f32x4 zero = {0.f, 0.f, 0.f, 0.f};
  #pragma unroll
  for (int m = 0; m < 8; ++m)
    #pragma unroll
    for (int n = 0; n < 4; ++n) acc[m][n] = zero;

  gemm_core256_fp8(s, As, Bs, wid, rA, rB, off0, off1, acc);

  const float LN2 = 0.69314718055994530942f;
  float sAll = 0.f, sPos = 0.f, sDiag = 0.f;
  #pragma unroll
  for (int m = 0; m < 8; ++m) {
    #pragma unroll
    for (int j = 0; j < 4; ++j) {
      const int lr = wr * 128 + m * 16 + (lane >> 4) * 4 + j;
      const long long rowg = brow + lr;
      if (rowg < N_PAD) {
        const int bg = sbatch[lr];
        #pragma unroll
        for (int n = 0; n < 4; ++n) {
          const int col = (int)bcol + wc * 64 + n * 16 + (lane & 15);
          float v = acc[m][n][j];
          float t = __expf(-fabsf(v));
          float spn = fmaxf(-v, 0.f) + __logf(1.0f + t);   // softplus(-v)
          sAll += spn + v;
          if (col == bg) {
            sPos += LN2 - spn;
            sDiag += spn + v;
          }
        }
      }
    }
  }
  #pragma unroll
  for (int off = 32; off > 0; off >>= 1) {
    sAll  += __shfl_down(sAll, off);
    sPos  += __shfl_down(sPos, off);
    sDiag += __shfl_down(sDiag, off);
  }
  if (lane == 0) { sred[wid] = sPos; sred[8 + wid] = sAll; sred[16 + wid] = sDiag; }
  __syncthreads();
  if (tid == 0) {
    float p = 0.f, a = 0.f, d = 0.f;
    #pragma unroll
    for (int w = 0; w < 8; ++w) { p += sred[w]; a += sred[8 + w]; d += sred[16 + w]; }
    atomicAdd(accum,     (double)p);
    atomicAdd(accum + 1, (double)a);
    atomicAdd(accum + 2, (double)d);
  }
}

__global__ void finalize_kernel(const double* __restrict__ accum,
                                float* __restrict__ out) {
  if (threadIdx.x == 0 && blockIdx.x == 0) {
    const double LN2 = 0.6931471805599453094172321;
    double posSum = accum[0];
    double negSum = (accum[1] - accum[2])
                  - ((double)N_PAD * N_GRAPH - (double)N_NODE) * LN2;
    double Epos = posSum / (double)N_NODE;
    double Eneg = negSum / ((double)N_NODE * (double)(N_GRAPH - 1));
    out[0] = (float)(Eneg - Epos);
  }
}

// ---- launch -----------------------------------------------------------------

extern "C" void kernel_launch(void* const* d_in, const int* in_sizes, int n_in,
                              void* d_out, int out_size, void* d_ws, size_t ws_size,
                              hipStream_t stream) {
  const float* node  = (const float*)d_in[0];
  const float* graph = (const float*)d_in[1];
  const int*   batch = (const int*)d_in[2];
  const float* lw0 = (const float*)d_in[3];
  const float* lb0 = (const float*)d_in[4];
  const float* lw1 = (const float*)d_in[5];
  const float* lb1 = (const float*)d_in[6];
  const float* lw2 = (const float*)d_in[7];
  const float* lb2 = (const float*)d_in[8];
  const float* lws = (const float*)d_in[9];
  const float* lbs = (const float*)d_in[10];
  const float* gw0 = (const float*)d_in[11];
  const float* gb0 = (const float*)d_in[12];
  const float* gw1 = (const float*)d_in[13];
  const float* gb1 = (const float*)d_in[14];
  const float* gw2 = (const float*)d_in[15];
  const float* gb2 = (const float*)d_in[16];
  const float* gws = (const float*)d_in[17];
  const float* gbs = (const float*)d_in[18];

  // workspace layout (identical to R2-R7); l_enc/g_enc fp8 overlay H1/GH1
  char* ws = (char*)d_ws;
  double*         accum = (double*)ws;                          // 24 B
  unsigned short* WB  = (unsigned short*)(ws + 256);            // 8 x 512x512 bf16
  unsigned short* XB  = (unsigned short*)(ws + 4194560LL);      // [N_PAD,512] bf16
  unsigned short* H1  = (unsigned short*)(ws + 55443712LL);     // h1 bf16; later l_enc fp8
  unsigned short* H2  = (unsigned short*)(ws + 106692864LL);
  unsigned short* GXB = (unsigned short*)(ws + 157942016LL);
  unsigned short* GH1 = (unsigned short*)(ws + 158990592LL);    // gh1 bf16; later g_enc fp8
  unsigned short* GH2 = (unsigned short*)(ws + 160039168LL);
  if (ws_size < 161087744ULL) return;

  hipMemsetAsync(accum, 0, 32, stream);

  WPtrs wp;
  wp.p[0] = lw0; wp.p[1] = lw1; wp.p[2] = lw2; wp.p[3] = lws;
  wp.p[4] = gw0; wp.p[5] = gw1; wp.p[6] = gw2; wp.p[7] = gws;
  cast_w_kernel<<<1024, 256, 0, stream>>>(wp, WB);
  cast_pad_kernel<<<12512, 256, 0, stream>>>(node, XB, N_NODE, N_PAD);
  cast_pad_kernel<<<256, 256, 0, stream>>>(graph, GXB, N_GRAPH, N_GRAPH);

  // ---- ff chain: 128² bf16 kernels, combined l+g grid ----
  dim3 blk256(256);
  const int nwgL = 4 * 391;
  const int nwgG = 4 * 8;
  dim3 gff(nwgL + nwgG);

  gemm_ff_kernel<0><<<gff, blk256, 0, stream>>>(
      XB, WB + 0 * 262144, lb0, H1, nullptr, nullptr, nullptr, nwgL,
      GXB, WB + 4 * 262144, gb0, GH1, nullptr, nullptr, nullptr);
  gemm_ff_kernel<0><<<gff, blk256, 0, stream>>>(
      H1, WB + 1 * 262144, lb1, H2, nullptr, nullptr, nullptr, nwgL,
      GH1, WB + 5 * 262144, gb1, GH2, nullptr, nullptr, nullptr);
  // DUAL: reads H2+XB (l) / GH2+GXB (g), writes fp8 enc into H1/GH1 regions
  gemm_ff_kernel<1><<<gff, blk256, 0, stream>>>(
      H2, WB + 2 * 262144, lb2, H1, XB, WB + 3 * 262144, lbs, nwgL,
      GH2, WB + 6 * 262144, gb2, GH1, GXB, WB + 7 * 262144, gbs);

  zeropad8_kernel<<<6, 256, 0, stream>>>((unsigned char*)H1);

  // ---- jsd: 256² fp8 single-tile kernel ----
  dim3 blk512(512);
  dim3 gr(196 * 4);                   // 784 blocks
  gemm_jsd256<<<gr, blk512, 0, stream>>>(
      (const unsigned char*)H1, (const unsigned char*)GH1, batch, accum);
  finalize_kernel<<<1, 64, 0, stream>>>(accum, (float*)d_out);
}

// Round 10
// 335.079 us; speedup vs baseline: 1.0216x; 1.0216x over previous
//
#include <hip/hip_runtime.h>
#include <hip/hip_bf16.h>

#define N_NODE  50000
#define N_PAD   50048   // 391 * 128
#define N_GRAPH 1024
#define DD      512
// 128-tile bf16 core (ff):
#define BK      64
#define NT      (DD / BK)   // 8 K-steps
// 128-tile fp8 core (jsd): 64-byte K-step
#define NK8     8           // 512 / 64

typedef __attribute__((ext_vector_type(8))) short bf16x8;
typedef __attribute__((ext_vector_type(4))) float f32x4;

__device__ __forceinline__ unsigned short f2bf(float f) {
  unsigned int u = __builtin_bit_cast(unsigned int, f);
  return (unsigned short)((u + 0x7FFFu + ((u >> 16) & 1u)) >> 16);  // RTN-even
}

// fp32 -> fp8 e4m3fn, RNE, BRANCHLESS (R8 lesson: early-returns diverge)
__device__ __forceinline__ unsigned char f2fp8(float f) {
  unsigned int u = __builtin_bit_cast(unsigned int, f);
  unsigned int sg = (u >> 24) & 0x80u;
  float a = __builtin_bit_cast(float, u & 0x7fffffffu);
  a = fminf(a, 448.0f);
  unsigned int r = __builtin_bit_cast(unsigned int, a);
  unsigned int rn = r + 0x7ffffu + ((r >> 20) & 1u);   // RNE at mantissa bit 20
  int codeN = (int)(rn >> 20) - (120 << 3);            // ((e+127)<<3|m3) - 960
  int codeS = (int)rintf(a * 512.0f);                  // subnormal grid 2^-9
  int code = (a >= 0.015625f) ? codeN : codeS;
  code = code > 0x7E ? 0x7E : code;
  return (unsigned char)(sg | (unsigned int)code);
}

__device__ __forceinline__ void gload16(const void* g, void* l) {
  __builtin_amdgcn_global_load_lds(
      (const __attribute__((address_space(1))) unsigned int*)g,
      (__attribute__((address_space(3))) unsigned int*)l, 16, 0, 0);
}

// T1: bijective XCD-chunk remap (m204 variant)
__device__ __forceinline__ int xcd_remap(int bid, int nwg) {
  int xcd = bid & 7;
  int local = bid >> 3;
  int q = nwg >> 3, r = nwg & 7;
  int base = (xcd < r) ? xcd * (q + 1) : r * (q + 1) + (xcd - r) * q;
  return base + local;
}

// ---- cast kernels -----------------------------------------------------------

__global__ void cast_pad_kernel(const float* __restrict__ src,
                                unsigned short* __restrict__ dst,
                                int srcRows, int dstRows) {
  long long base = ((long long)blockIdx.x * blockDim.x + threadIdx.x) * 8;
  if (base >= (long long)dstRows * DD) return;
  int row = (int)(base >> 9);
  bf16x8 o;
  if (row < srcRows) {
    float4 x0 = reinterpret_cast<const float4*>(src + base)[0];
    float4 x1 = reinterpret_cast<const float4*>(src + base)[1];
    o[0] = (short)f2bf(x0.x); o[1] = (short)f2bf(x0.y);
    o[2] = (short)f2bf(x0.z); o[3] = (short)f2bf(x0.w);
    o[4] = (short)f2bf(x1.x); o[5] = (short)f2bf(x1.y);
    o[6] = (short)f2bf(x1.z); o[7] = (short)f2bf(x1.w);
  } else {
    for (int i = 0; i < 8; ++i) o[i] = 0;
  }
  *reinterpret_cast<bf16x8*>(dst + base) = o;
}

struct WPtrs { const float* p[8]; };

__global__ void cast_w_kernel(WPtrs ps, unsigned short* __restrict__ dst) {
  long long base = ((long long)blockIdx.x * blockDim.x + threadIdx.x) * 8;
  int mat = (int)(base >> 18);
  int off = (int)(base & 262143LL);
  const float* s = ps.p[mat] + off;
  float4 x0 = reinterpret_cast<const float4*>(s)[0];
  float4 x1 = reinterpret_cast<const float4*>(s)[1];
  bf16x8 o;
  o[0] = (short)f2bf(x0.x); o[1] = (short)f2bf(x0.y);
  o[2] = (short)f2bf(x0.z); o[3] = (short)f2bf(x0.w);
  o[4] = (short)f2bf(x1.x); o[5] = (short)f2bf(x1.y);
  o[6] = (short)f2bf(x1.z); o[7] = (short)f2bf(x1.w);
  *reinterpret_cast<bf16x8*>(dst + base) = o;
}

__global__ void zeropad8_kernel(unsigned char* __restrict__ H) {
  long long i = (long long)blockIdx.x * blockDim.x + threadIdx.x;
  long long base = (long long)N_NODE * DD + i * 16;
  if (base < (long long)N_PAD * DD) {
    int4 z = {0, 0, 0, 0};
    *reinterpret_cast<int4*>(H + base) = z;
  }
}

// ============================================================================
// ff side: R2's measured-good 128x128 bf16 core (depth-1 prefetch, BK=64)
// ============================================================================

__device__ __forceinline__ void stage_tile(const unsigned short* __restrict__ G,
                                           long long rowBase, int kcol,
                                           unsigned short* lds, int tid) {
  const int rr   = tid >> 3;
  const int csrc = (tid & 7) ^ (rr & 7);
  const unsigned short* src = G + (rowBase + rr) * DD + kcol + csrc * 8;
  unsigned short* dstbase = lds + ((tid >> 6) << 9);
  #pragma unroll
  for (int r = 0; r < 4; ++r)
    gload16(src + (long long)r * 32 * DD, dstbase + r * 2048);
}

__device__ __forceinline__ void gemm_core64(
    const unsigned short* __restrict__ A, const unsigned short* __restrict__ B,
    unsigned short* As, unsigned short* Bs,
    long long brow, long long bcol, int wr, int wc, int lane, int tid,
    f32x4 acc[4][4]) {
  const int rA = wr * 64 + (lane & 15);
  const int rB = wc * 64 + (lane & 15);
  const int c16b = lane >> 4;

  stage_tile(A, brow, 0, As, tid);
  stage_tile(B, bcol, 0, Bs, tid);
  __syncthreads();

  for (int kt = 0; kt < NT; ++kt) {
    const int cur = kt & 1;
    if (kt + 1 < NT) {
      stage_tile(A, brow, (kt + 1) * BK, As + (cur ^ 1) * 8192, tid);
      stage_tile(B, bcol, (kt + 1) * BK, Bs + (cur ^ 1) * 8192, tid);
    }
    const unsigned short* as = As + cur * 8192;
    const unsigned short* bs = Bs + cur * 8192;
    #pragma unroll
    for (int kk = 0; kk < 2; ++kk) {
      bf16x8 a[4], b[4];
      #pragma unroll
      for (int m = 0; m < 4; ++m) {
        const int row = rA + m * 16;
        const int c16 = (c16b + kk * 4) ^ (row & 7);
        a[m] = *reinterpret_cast<const bf16x8*>(as + row * 64 + c16 * 8);
      }
      #pragma unroll
      for (int n = 0; n < 4; ++n) {
        const int row = rB + n * 16;
        const int c16 = (c16b + kk * 4) ^ (row & 7);
        b[n] = *reinterpret_cast<const bf16x8*>(bs + row * 64 + c16 * 8);
      }
      #pragma unroll
      for (int m = 0; m < 4; ++m)
        #pragma unroll
        for (int n = 0; n < 4; ++n)
          acc[m][n] = __builtin_amdgcn_mfma_f32_16x16x32_bf16(a[m], b[n], acc[m][n], 0, 0, 0);
    }
    __syncthreads();
  }
}

// ---- FF GEMM: C = relu(A@W^T + bias); DUAL writes fp8 (relu(h2W2+b2)+xWs+bs)

template <int DUAL>
__global__ __launch_bounds__(256, 2) void gemm_ff_kernel(
    const unsigned short* __restrict__ Al, const unsigned short* __restrict__ Wl,
    const float* __restrict__ biasl, unsigned short* __restrict__ Cl,
    const unsigned short* __restrict__ A2l, const unsigned short* __restrict__ W2l,
    const float* __restrict__ bias2l, int nwgL,
    const unsigned short* __restrict__ Ag, const unsigned short* __restrict__ Wg,
    const float* __restrict__ biasg, unsigned short* __restrict__ Cg,
    const unsigned short* __restrict__ A2g, const unsigned short* __restrict__ W2g,
    const float* __restrict__ bias2g) {
  __shared__ unsigned short As[2 * 8192];
  __shared__ unsigned short Bs[2 * 8192];
  const int tid = threadIdx.x;
  const int lane = tid & 63, wid = tid >> 6;
  const int wr = wid >> 1, wc = wid & 1;

  int tile = xcd_remap(blockIdx.x, gridDim.x);
  const unsigned short *A, *W, *A2, *W2;
  const float *bias, *bias2;
  unsigned short* C;
  if (tile < nwgL) {
    A = Al; W = Wl; bias = biasl; C = Cl; A2 = A2l; W2 = W2l; bias2 = bias2l;
  } else {
    tile -= nwgL;
    A = Ag; W = Wg; bias = biasg; C = Cg; A2 = A2g; W2 = W2g; bias2 = bias2g;
  }
  const long long brow = (long long)(tile >> 2) * 128;
  const long long bcol = (long long)(tile & 3) * 128;

  f32x4 zero = {0.f, 0.f, 0.f, 0.f};
  f32x4 acc[4][4];
  #pragma unroll
  for (int m = 0; m < 4; ++m)
    #pragma unroll
    for (int n = 0; n < 4; ++n) acc[m][n] = zero;

  gemm_core64(A, W, As, Bs, brow, bcol, wr, wc, lane, tid, acc);

  float bv[4];
  #pragma unroll
  for (int n = 0; n < 4; ++n) bv[n] = bias[bcol + wc * 64 + n * 16 + (lane & 15)];

  if constexpr (DUAL) {
    float r[4][4][4];
    #pragma unroll
    for (int m = 0; m < 4; ++m)
      #pragma unroll
      for (int n = 0; n < 4; ++n)
        #pragma unroll
        for (int j = 0; j < 4; ++j)
          r[m][n][j] = fmaxf(acc[m][n][j] + bv[n], 0.f);
    #pragma unroll
    for (int m = 0; m < 4; ++m)
      #pragma unroll
      for (int n = 0; n < 4; ++n) acc[m][n] = zero;

    gemm_core64(A2, W2, As, Bs, brow, bcol, wr, wc, lane, tid, acc);

    float b2[4];
    #pragma unroll
    for (int n = 0; n < 4; ++n) b2[n] = bias2[bcol + wc * 64 + n * 16 + (lane & 15)];

    unsigned char* C8 = (unsigned char*)C;   // DUAL output is fp8 e4m3
    #pragma unroll
    for (int m = 0; m < 4; ++m) {
      const long long row = brow + wr * 64 + m * 16 + (lane >> 4) * 4;
      #pragma unroll
      for (int j = 0; j < 4; ++j)
        #pragma unroll
        for (int n = 0; n < 4; ++n) {
          const long long col = bcol + wc * 64 + n * 16 + (lane & 15);
          float v = r[m][n][j] + acc[m][n][j] + b2[n];
          C8[(row + j) * DD + col] = f2fp8(v);
        }
    }
  } else {
    #pragma unroll
    for (int m = 0; m < 4; ++m) {
      const long long row = brow + wr * 64 + m * 16 + (lane >> 4) * 4;
      #pragma unroll
      for (int j = 0; j < 4; ++j)
        #pragma unroll
        for (int n = 0; n < 4; ++n) {
          const long long col = bcol + wc * 64 + n * 16 + (lane & 15);
          float v = fmaxf(acc[m][n][j] + bv[n], 0.f);
          C[(row + j) * DD + col] = f2bf(v);
        }
    }
  }
}

// ============================================================================
// jsd side: fp8 on R2's proven 128² SHAPE — 256 threads, 2x2 waves, 2-slot
// depth-1 LDS (32 KB total) -> 3 blocks/CU (12 waves/CU). 64-B rows, same
// slot-swizzle family as R4 (verified): phys 16B-slot p of row r holds
// logical p ^ ((r>>1)&3); inverse applied on global source (rule 21).
// ============================================================================

__device__ __forceinline__ void stage8(const unsigned char* __restrict__ G,
                                       long long rowBase, int kbyte,
                                       unsigned char* lds, int tid) {
  const int rr   = tid >> 2;                              // 0..63
  const int csrc = ((tid & 3) ^ ((tid >> 3) & 3)) * 16;   // inverse-swizzled
  const unsigned char* src = G + (rowBase + rr) * DD + kbyte + csrc;
  unsigned char* dst = lds + ((tid >> 6) << 10);          // wid*1024 (uniform)
  gload16(src, dst);
  gload16(src + 64LL * DD, dst + 4096);                   // rows +64
}

// accum[0] = sum_diag (LN2 - softplus(-v))
// accum[1] = sum_all  (softplus(-v) + v)   (zero-pad rows -> ln2, cancelled)
// accum[2] = sum_diag (softplus(-v) + v)

__global__ __launch_bounds__(256, 3) void gemm_jsd128f8(
    const unsigned char* __restrict__ A, const unsigned char* __restrict__ B,
    const int* __restrict__ batch, double* __restrict__ accum) {
  __shared__ unsigned char As8[2 * 8192];
  __shared__ unsigned char Bs8[2 * 8192];
  __shared__ int sbatch[128];
  __shared__ float sred[12];
  const int tid = threadIdx.x;
  const int lane = tid & 63, wid = tid >> 6;
  const int wr = wid >> 1, wc = wid & 1;

  const int tile = xcd_remap(blockIdx.x, gridDim.x);   // 3128 = 8*391
  const long long brow = (long long)(tile >> 3) * 128;
  const long long bcol = (long long)(tile & 7) * 128;

  if (tid < 128) {
    long long gr = brow + tid;
    sbatch[tid] = (gr < N_NODE) ? batch[gr] : -1;
  }

  const int rA = wr * 64 + (lane & 15);
  const int rB = wc * 64 + (lane & 15);
  const int qa = lane >> 4;                      // K-group 0..3
  const int sa = ((lane & 15) >> 1) & 3;         // row swizzle key
  const int off0 = (((qa >> 1) ^ sa) << 4) + ((qa & 1) << 3);          // kk=0
  const int off1 = (((2 + (qa >> 1)) ^ sa) << 4) + ((qa & 1) << 3);    // kk=1

  f32x4 acc[4][4];
  f32x4 zero = {0.f, 0.f, 0.f, 0.f};
  #pragma unroll
  for (int m = 0; m < 4; ++m)
    #pragma unroll
    for (int n = 0; n < 4; ++n) acc[m][n] = zero;

  stage8(A, brow, 0, As8, tid);
  stage8(B, bcol, 0, Bs8, tid);
  __syncthreads();

  for (int kt = 0; kt < NK8; ++kt) {
    const int cur = kt & 1;
    if (kt + 1 < NK8) {
      stage8(A, brow, (kt + 1) * 64, As8 + (cur ^ 1) * 8192, tid);
      stage8(B, bcol, (kt + 1) * 64, Bs8 + (cur ^ 1) * 8192, tid);
    }
    const unsigned char* as = As8 + cur * 8192;
    const unsigned char* bs = Bs8 + cur * 8192;
    #pragma unroll
    for (int kk = 0; kk < 2; ++kk) {
      const int off = kk ? off1 : off0;
      long long a[4], b[4];
      #pragma unroll
      for (int m = 0; m < 4; ++m)
        a[m] = *reinterpret_cast<const long long*>(as + (rA + m * 16) * 64 + off);
      #pragma unroll
      for (int n = 0; n < 4; ++n)
        b[n] = *reinterpret_cast<const long long*>(bs + (rB + n * 16) * 64 + off);
      __builtin_amdgcn_s_setprio(1);
      #pragma unroll
      for (int m = 0; m < 4; ++m)
        #pragma unroll
        for (int n = 0; n < 4; ++n)
          acc[m][n] = __builtin_amdgcn_mfma_f32_16x16x32_fp8_fp8(a[m], b[n], acc[m][n], 0, 0, 0);
      __builtin_amdgcn_s_setprio(0);
    }
    __syncthreads();
  }

  const float LN2 = 0.69314718055994530942f;
  float sAll = 0.f, sPos = 0.f, sDiag = 0.f;
  #pragma unroll
  for (int m = 0; m < 4; ++m) {
    #pragma unroll
    for (int j = 0; j < 4; ++j) {
      const int lr = wr * 64 + m * 16 + (lane >> 4) * 4 + j;
      const int bg = sbatch[lr];
      #pragma unroll
      for (int n = 0; n < 4; ++n) {
        const int col = (int)bcol + wc * 64 + n * 16 + (lane & 15);
        float v = acc[m][n][j];
        float t = __expf(-fabsf(v));
        float spn = fmaxf(-v, 0.f) + __logf(1.0f + t);   // softplus(-v)
        sAll += spn + v;
        if (col == bg) {
          sPos += LN2 - spn;
          sDiag += spn + v;
        }
      }
    }
  }
  #pragma unroll
  for (int off = 32; off > 0; off >>= 1) {
    sAll  += __shfl_down(sAll, off);
    sPos  += __shfl_down(sPos, off);
    sDiag += __shfl_down(sDiag, off);
  }
  if (lane == 0) { sred[wid] = sPos; sred[4 + wid] = sAll; sred[8 + wid] = sDiag; }
  __syncthreads();
  if (tid == 0) {
    float p = sred[0] + sred[1] + sred[2] + sred[3];
    float a = sred[4] + sred[5] + sred[6] + sred[7];
    float d = sred[8] + sred[9] + sred[10] + sred[11];
    atomicAdd(accum,     (double)p);
    atomicAdd(accum + 1, (double)a);
    atomicAdd(accum + 2, (double)d);
  }
}

__global__ void finalize_kernel(const double* __restrict__ accum,
                                float* __restrict__ out) {
  if (threadIdx.x == 0 && blockIdx.x == 0) {
    const double LN2 = 0.6931471805599453094172321;
    double posSum = accum[0];
    double negSum = (accum[1] - accum[2])
                  - ((double)N_PAD * N_GRAPH - (double)N_NODE) * LN2;
    double Epos = posSum / (double)N_NODE;
    double Eneg = negSum / ((double)N_NODE * (double)(N_GRAPH - 1));
    out[0] = (float)(Eneg - Epos);
  }
}

// ---- launch -----------------------------------------------------------------

extern "C" void kernel_launch(void* const* d_in, const int* in_sizes, int n_in,
                              void* d_out, int out_size, void* d_ws, size_t ws_size,
                              hipStream_t stream) {
  const float* node  = (const float*)d_in[0];
  const float* graph = (const float*)d_in[1];
  const int*   batch = (const int*)d_in[2];
  const float* lw0 = (const float*)d_in[3];
  const float* lb0 = (const float*)d_in[4];
  const float* lw1 = (const float*)d_in[5];
  const float* lb1 = (const float*)d_in[6];
  const float* lw2 = (const float*)d_in[7];
  const float* lb2 = (const float*)d_in[8];
  const float* lws = (const float*)d_in[9];
  const float* lbs = (const float*)d_in[10];
  const float* gw0 = (const float*)d_in[11];
  const float* gb0 = (const float*)d_in[12];
  const float* gw1 = (const float*)d_in[13];
  const float* gb1 = (const float*)d_in[14];
  const float* gw2 = (const float*)d_in[15];
  const float* gb2 = (const float*)d_in[16];
  const float* gws = (const float*)d_in[17];
  const float* gbs = (const float*)d_in[18];

  // workspace layout (identical to R2-R8); l_enc/g_enc fp8 overlay H1/GH1
  char* ws = (char*)d_ws;
  double*         accum = (double*)ws;                          // 24 B
  unsigned short* WB  = (unsigned short*)(ws + 256);            // 8 x 512x512 bf16
  unsigned short* XB  = (unsigned short*)(ws + 4194560LL);      // [N_PAD,512] bf16
  unsigned short* H1  = (unsigned short*)(ws + 55443712LL);     // h1 bf16; later l_enc fp8
  unsigned short* H2  = (unsigned short*)(ws + 106692864LL);
  unsigned short* GXB = (unsigned short*)(ws + 157942016LL);
  unsigned short* GH1 = (unsigned short*)(ws + 158990592LL);    // gh1 bf16; later g_enc fp8
  unsigned short* GH2 = (unsigned short*)(ws + 160039168LL);
  if (ws_size < 161087744ULL) return;

  hipMemsetAsync(accum, 0, 32, stream);

  WPtrs wp;
  wp.p[0] = lw0; wp.p[1] = lw1; wp.p[2] = lw2; wp.p[3] = lws;
  wp.p[4] = gw0; wp.p[5] = gw1; wp.p[6] = gw2; wp.p[7] = gws;
  cast_w_kernel<<<1024, 256, 0, stream>>>(wp, WB);
  cast_pad_kernel<<<12512, 256, 0, stream>>>(node, XB, N_NODE, N_PAD);
  cast_pad_kernel<<<256, 256, 0, stream>>>(graph, GXB, N_GRAPH, N_GRAPH);

  // ---- ff chain: 128² bf16 kernels, combined l+g grid ----
  dim3 blk256(256);
  const int nwgL = 4 * 391;
  const int nwgG = 4 * 8;
  dim3 gff(nwgL + nwgG);

  gemm_ff_kernel<0><<<gff, blk256, 0, stream>>>(
      XB, WB + 0 * 262144, lb0, H1, nullptr, nullptr, nullptr, nwgL,
      GXB, WB + 4 * 262144, gb0, GH1, nullptr, nullptr, nullptr);
  gemm_ff_kernel<0><<<gff, blk256, 0, stream>>>(
      H1, WB + 1 * 262144, lb1, H2, nullptr, nullptr, nullptr, nwgL,
      GH1, WB + 5 * 262144, gb1, GH2, nullptr, nullptr, nullptr);
  // DUAL: reads H2+XB (l) / GH2+GXB (g), writes fp8 enc into H1/GH1 regions
  gemm_ff_kernel<1><<<gff, blk256, 0, stream>>>(
      H2, WB + 2 * 262144, lb2, H1, XB, WB + 3 * 262144, lbs, nwgL,
      GH2, WB + 6 * 262144, gb2, GH1, GXB, WB + 7 * 262144, gbs);

  zeropad8_kernel<<<6, 256, 0, stream>>>((unsigned char*)H1);

  // ---- jsd: 128² fp8 kernel, 3 blocks/CU ----
  dim3 gr(8 * 391);                   // 3128 blocks
  gemm_jsd128f8<<<gr, blk256, 0, stream>>>(
      (const unsigned char*)H1, (const unsigned char*)GH1, batch, accum);
  finalize_kernel<<<1, 64, 0, stream>>>(accum, (float*)d_out);
}

// Round 11
// 294.322 us; speedup vs baseline: 1.1630x; 1.1385x over previous
//
#include <hip/hip_runtime.h>
#include <hip/hip_bf16.h>

#define N_NODE  50000
#define N_PAD   50048   // 391 * 128
#define N_GRAPH 1024
#define DD      512
// 128-tile bf16 core (ff):
#define BK      64
#define NT      (DD / BK)   // 8 K-steps
// 256-tile fp8 core (jsd): 64-elem K-step
#define NKT8    8           // 512 / 64

typedef __attribute__((ext_vector_type(8))) short bf16x8;
typedef __attribute__((ext_vector_type(4))) float f32x4;
typedef __attribute__((ext_vector_type(2))) long long ll2;

__device__ __forceinline__ unsigned short f2bf(float f) {
  unsigned int u = __builtin_bit_cast(unsigned int, f);
  return (unsigned short)((u + 0x7FFFu + ((u >> 16) & 1u)) >> 16);  // RTN-even
}

// fp32 -> fp8 e4m3fn, RNE, BRANCHLESS (R8 lesson: early-returns diverge)
__device__ __forceinline__ unsigned char f2fp8(float f) {
  unsigned int u = __builtin_bit_cast(unsigned int, f);
  unsigned int sg = (u >> 24) & 0x80u;
  float a = __builtin_bit_cast(float, u & 0x7fffffffu);
  a = fminf(a, 448.0f);
  unsigned int r = __builtin_bit_cast(unsigned int, a);
  unsigned int rn = r + 0x7ffffu + ((r >> 20) & 1u);   // RNE at mantissa bit 20
  int codeN = (int)(rn >> 20) - (120 << 3);            // ((e+127)<<3|m3) - 960
  int codeS = (int)rintf(a * 512.0f);                  // subnormal grid 2^-9
  int code = (a >= 0.015625f) ? codeN : codeS;
  code = code > 0x7E ? 0x7E : code;
  return (unsigned char)(sg | (unsigned int)code);
}

// K-permutation for fp8 enc buffers: within each 64-col group, physical
// position p holds original k: p = qa*16 + kk*8 + j for k = kk*32 + qa*8 + j.
// Maps a lane's two MFMA kk-operands to 16 CONTIGUOUS bytes (one b128 read).
__device__ __forceinline__ long long permute_col(long long c) {
  int o = (int)c & 63;
  int p = (((o >> 3) & 3) << 4) | ((o >> 5) << 3) | (o & 7);
  return (c & ~63LL) | p;
}

__device__ __forceinline__ void gload16(const void* g, void* l) {
  __builtin_amdgcn_global_load_lds(
      (const __attribute__((address_space(1))) unsigned int*)g,
      (__attribute__((address_space(3))) unsigned int*)l, 16, 0, 0);
}

// T1: bijective XCD-chunk remap (m204 variant)
__device__ __forceinline__ int xcd_remap(int bid, int nwg) {
  int xcd = bid & 7;
  int local = bid >> 3;
  int q = nwg >> 3, r = nwg & 7;
  int base = (xcd < r) ? xcd * (q + 1) : r * (q + 1) + (xcd - r) * q;
  return base + local;
}

// ---- cast kernels -----------------------------------------------------------

__global__ void cast_pad_kernel(const float* __restrict__ src,
                                unsigned short* __restrict__ dst,
                                int srcRows, int dstRows) {
  long long base = ((long long)blockIdx.x * blockDim.x + threadIdx.x) * 8;
  if (base >= (long long)dstRows * DD) return;
  int row = (int)(base >> 9);
  bf16x8 o;
  if (row < srcRows) {
    float4 x0 = reinterpret_cast<const float4*>(src + base)[0];
    float4 x1 = reinterpret_cast<const float4*>(src + base)[1];
    o[0] = (short)f2bf(x0.x); o[1] = (short)f2bf(x0.y);
    o[2] = (short)f2bf(x0.z); o[3] = (short)f2bf(x0.w);
    o[4] = (short)f2bf(x1.x); o[5] = (short)f2bf(x1.y);
    o[6] = (short)f2bf(x1.z); o[7] = (short)f2bf(x1.w);
  } else {
    for (int i = 0; i < 8; ++i) o[i] = 0;
  }
  *reinterpret_cast<bf16x8*>(dst + base) = o;
}

struct WPtrs { const float* p[8]; };

__global__ void cast_w_kernel(WPtrs ps, unsigned short* __restrict__ dst) {
  long long base = ((long long)blockIdx.x * blockDim.x + threadIdx.x) * 8;
  int mat = (int)(base >> 18);
  int off = (int)(base & 262143LL);
  const float* s = ps.p[mat] + off;
  float4 x0 = reinterpret_cast<const float4*>(s)[0];
  float4 x1 = reinterpret_cast<const float4*>(s)[1];
  bf16x8 o;
  o[0] = (short)f2bf(x0.x); o[1] = (short)f2bf(x0.y);
  o[2] = (short)f2bf(x0.z); o[3] = (short)f2bf(x0.w);
  o[4] = (short)f2bf(x1.x); o[5] = (short)f2bf(x1.y);
  o[6] = (short)f2bf(x1.z); o[7] = (short)f2bf(x1.w);
  *reinterpret_cast<bf16x8*>(dst + base) = o;
}

__global__ void zeropad8_kernel(unsigned char* __restrict__ H) {
  long long i = (long long)blockIdx.x * blockDim.x + threadIdx.x;
  long long base = (long long)N_NODE * DD + i * 16;
  if (base < (long long)N_PAD * DD) {
    int4 z = {0, 0, 0, 0};
    *reinterpret_cast<int4*>(H + base) = z;
  }
}

// ============================================================================
// ff side: R2's measured-good 128x128 bf16 core (depth-1 prefetch, BK=64)
// ============================================================================

__device__ __forceinline__ void stage_tile(const unsigned short* __restrict__ G,
                                           long long rowBase, int kcol,
                                           unsigned short* lds, int tid) {
  const int rr   = tid >> 3;
  const int csrc = (tid & 7) ^ (rr & 7);
  const unsigned short* src = G + (rowBase + rr) * DD + kcol + csrc * 8;
  unsigned short* dstbase = lds + ((tid >> 6) << 9);
  #pragma unroll
  for (int r = 0; r < 4; ++r)
    gload16(src + (long long)r * 32 * DD, dstbase + r * 2048);
}

__device__ __forceinline__ void gemm_core64(
    const unsigned short* __restrict__ A, const unsigned short* __restrict__ B,
    unsigned short* As, unsigned short* Bs,
    long long brow, long long bcol, int wr, int wc, int lane, int tid,
    f32x4 acc[4][4]) {
  const int rA = wr * 64 + (lane & 15);
  const int rB = wc * 64 + (lane & 15);
  const int c16b = lane >> 4;

  stage_tile(A, brow, 0, As, tid);
  stage_tile(B, bcol, 0, Bs, tid);
  __syncthreads();

  for (int kt = 0; kt < NT; ++kt) {
    const int cur = kt & 1;
    if (kt + 1 < NT) {
      stage_tile(A, brow, (kt + 1) * BK, As + (cur ^ 1) * 8192, tid);
      stage_tile(B, bcol, (kt + 1) * BK, Bs + (cur ^ 1) * 8192, tid);
    }
    const unsigned short* as = As + cur * 8192;
    const unsigned short* bs = Bs + cur * 8192;
    #pragma unroll
    for (int kk = 0; kk < 2; ++kk) {
      bf16x8 a[4], b[4];
      #pragma unroll
      for (int m = 0; m < 4; ++m) {
        const int row = rA + m * 16;
        const int c16 = (c16b + kk * 4) ^ (row & 7);
        a[m] = *reinterpret_cast<const bf16x8*>(as + row * 64 + c16 * 8);
      }
      #pragma unroll
      for (int n = 0; n < 4; ++n) {
        const int row = rB + n * 16;
        const int c16 = (c16b + kk * 4) ^ (row & 7);
        b[n] = *reinterpret_cast<const bf16x8*>(bs + row * 64 + c16 * 8);
      }
      #pragma unroll
      for (int m = 0; m < 4; ++m)
        #pragma unroll
        for (int n = 0; n < 4; ++n)
          acc[m][n] = __builtin_amdgcn_mfma_f32_16x16x32_bf16(a[m], b[n], acc[m][n], 0, 0, 0);
    }
    __syncthreads();
  }
}

// ---- FF GEMM: C = relu(A@W^T + bias); DUAL writes PERMUTED fp8 enc ---------

template <int DUAL>
__global__ __launch_bounds__(256, 2) void gemm_ff_kernel(
    const unsigned short* __restrict__ Al, const unsigned short* __restrict__ Wl,
    const float* __restrict__ biasl, unsigned short* __restrict__ Cl,
    const unsigned short* __restrict__ A2l, const unsigned short* __restrict__ W2l,
    const float* __restrict__ bias2l, int nwgL,
    const unsigned short* __restrict__ Ag, const unsigned short* __restrict__ Wg,
    const float* __restrict__ biasg, unsigned short* __restrict__ Cg,
    const unsigned short* __restrict__ A2g, const unsigned short* __restrict__ W2g,
    const float* __restrict__ bias2g) {
  __shared__ unsigned short As[2 * 8192];
  __shared__ unsigned short Bs[2 * 8192];
  const int tid = threadIdx.x;
  const int lane = tid & 63, wid = tid >> 6;
  const int wr = wid >> 1, wc = wid & 1;

  int tile = xcd_remap(blockIdx.x, gridDim.x);
  const unsigned short *A, *W, *A2, *W2;
  const float *bias, *bias2;
  unsigned short* C;
  if (tile < nwgL) {
    A = Al; W = Wl; bias = biasl; C = Cl; A2 = A2l; W2 = W2l; bias2 = bias2l;
  } else {
    tile -= nwgL;
    A = Ag; W = Wg; bias = biasg; C = Cg; A2 = A2g; W2 = W2g; bias2 = bias2g;
  }
  const long long brow = (long long)(tile >> 2) * 128;
  const long long bcol = (long long)(tile & 3) * 128;

  f32x4 zero = {0.f, 0.f, 0.f, 0.f};
  f32x4 acc[4][4];
  #pragma unroll
  for (int m = 0; m < 4; ++m)
    #pragma unroll
    for (int n = 0; n < 4; ++n) acc[m][n] = zero;

  gemm_core64(A, W, As, Bs, brow, bcol, wr, wc, lane, tid, acc);

  float bv[4];
  #pragma unroll
  for (int n = 0; n < 4; ++n) bv[n] = bias[bcol + wc * 64 + n * 16 + (lane & 15)];

  if constexpr (DUAL) {
    float r[4][4][4];
    #pragma unroll
    for (int m = 0; m < 4; ++m)
      #pragma unroll
      for (int n = 0; n < 4; ++n)
        #pragma unroll
        for (int j = 0; j < 4; ++j)
          r[m][n][j] = fmaxf(acc[m][n][j] + bv[n], 0.f);
    #pragma unroll
    for (int m = 0; m < 4; ++m)
      #pragma unroll
      for (int n = 0; n < 4; ++n) acc[m][n] = zero;

    gemm_core64(A2, W2, As, Bs, brow, bcol, wr, wc, lane, tid, acc);

    float b2[4];
    #pragma unroll
    for (int n = 0; n < 4; ++n) b2[n] = bias2[bcol + wc * 64 + n * 16 + (lane & 15)];

    unsigned char* C8 = (unsigned char*)C;   // fp8 e4m3, K-PERMUTED layout
    #pragma unroll
    for (int m = 0; m < 4; ++m) {
      const long long row = brow + wr * 64 + m * 16 + (lane >> 4) * 4;
      #pragma unroll
      for (int j = 0; j < 4; ++j)
        #pragma unroll
        for (int n = 0; n < 4; ++n) {
          const long long col = bcol + wc * 64 + n * 16 + (lane & 15);
          float v = r[m][n][j] + acc[m][n][j] + b2[n];
          C8[(row + j) * DD + permute_col(col)] = f2fp8(v);
        }
    }
  } else {
    #pragma unroll
    for (int m = 0; m < 4; ++m) {
      const long long row = brow + wr * 64 + m * 16 + (lane >> 4) * 4;
      #pragma unroll
      for (int j = 0; j < 4; ++j)
        #pragma unroll
        for (int n = 0; n < 4; ++n) {
          const long long col = bcol + wc * 64 + n * 16 + (lane & 15);
          float v = fmaxf(acc[m][n][j] + bv[n], 0.f);
          C[(row + j) * DD + col] = f2bf(v);
        }
    }
  }
}

// ============================================================================
// jsd side: R8's 256x256 fp8 4-slot counted-vmcnt core, reads upgraded to one
// ds_read_b128 per fragment via the K-permuted layout. LDS stage = [256][64B];
// phys 16B-superslot p of row r holds logical p ^ ((r>>1)&3) (T2, rule 21).
// Per-lane read offset (qa ^ ((r>>1)&3))*16 is CONSTANT across m-frags
// (m*16>>1 ≡ 0 mod 4) -> precomputed; b128 bank pattern = 2 lanes/bank (free).
// ============================================================================

struct StageSrc8 { const unsigned char *a0, *a1, *b0, *b1; };

__device__ __forceinline__ void issue_stage8(const StageSrc8& s, int kbyte,
                                             unsigned char* sA, unsigned char* sB,
                                             int wid) {
  unsigned char* dA = sA + wid * 1024;   // wave-uniform; HW adds lane*16B
  unsigned char* dB = sB + wid * 1024;
  gload16(s.a0 + kbyte, dA);
  gload16(s.a1 + kbyte, dA + 8192);
  gload16(s.b0 + kbyte, dB);
  gload16(s.b1 + kbyte, dB + 8192);
}

__device__ __forceinline__ void gemm_core256_fp8(
    const StageSrc8& s, unsigned char* As, unsigned char* Bs,
    int wid, int rA, int rB, int offs, f32x4 acc[8][4]) {
  issue_stage8(s, 0, As, Bs, wid);
  issue_stage8(s, 64, As + 16384, Bs + 16384, wid);
  issue_stage8(s, 128, As + 32768, Bs + 32768, wid);
  #pragma unroll
  for (int t = 0; t < NKT8; ++t) {
    __builtin_amdgcn_sched_barrier(0);
    if (t < NKT8 - 2)       asm volatile("s_waitcnt vmcnt(8)" ::: "memory");
    else if (t == NKT8 - 2) asm volatile("s_waitcnt vmcnt(4)" ::: "memory");
    else                    asm volatile("s_waitcnt vmcnt(0)" ::: "memory");
    __builtin_amdgcn_s_barrier();
    __builtin_amdgcn_sched_barrier(0);
    if (t + 3 < NKT8)
      issue_stage8(s, (t + 3) * 64, As + ((t + 3) & 3) * 16384,
                   Bs + ((t + 3) & 3) * 16384, wid);
    const unsigned char* as = As + (t & 3) * 16384;
    const unsigned char* bs = Bs + (t & 3) * 16384;
    ll2 a[8], b[4];
    #pragma unroll
    for (int m = 0; m < 8; ++m)
      a[m] = *reinterpret_cast<const ll2*>(as + (rA + m * 16) * 64 + offs);
    #pragma unroll
    for (int n = 0; n < 4; ++n)
      b[n] = *reinterpret_cast<const ll2*>(bs + (rB + n * 16) * 64 + offs);
    __builtin_amdgcn_s_setprio(1);
    #pragma unroll
    for (int m = 0; m < 8; ++m)
      #pragma unroll
      for (int n = 0; n < 4; ++n)
        acc[m][n] = __builtin_amdgcn_mfma_f32_16x16x32_fp8_fp8(a[m][0], b[n][0], acc[m][n], 0, 0, 0);
    #pragma unroll
    for (int m = 0; m < 8; ++m)
      #pragma unroll
      for (int n = 0; n < 4; ++n)
        acc[m][n] = __builtin_amdgcn_mfma_f32_16x16x32_fp8_fp8(a[m][1], b[n][1], acc[m][n], 0, 0, 0);
    __builtin_amdgcn_s_setprio(0);
  }
}

// accum[0] = sum_diag (LN2 - softplus(-v))
// accum[1] = sum_all  (softplus(-v) + v)   (rows < N_PAD; zero rows -> ln2)
// accum[2] = sum_diag (softplus(-v) + v)

__global__ __launch_bounds__(512, 2) void gemm_jsd256(
    const unsigned char* __restrict__ A, const unsigned char* __restrict__ B,
    const int* __restrict__ batch, double* __restrict__ accum) {
  __shared__ unsigned char As[4 * 16384];
  __shared__ unsigned char Bs[4 * 16384];
  __shared__ int sbatch[256];
  __shared__ float sred[24];
  const int tid = threadIdx.x;
  const int lane = tid & 63, wid = tid >> 6;
  const int wr = wid >> 2, wc = wid & 3;

  const int tile = xcd_remap(blockIdx.x, gridDim.x);
  const long long brow = (long long)(tile >> 2) * 256;
  const long long bcol = (long long)(tile & 3) * 256;

  if (tid < 256) {
    long long gr = brow + tid;
    sbatch[tid] = (gr < N_NODE) ? batch[gr] : -1;
  }

  // staging: row rr = tid>>2, phys superslot p = tid&3 holds logical
  // p ^ ((rr>>1)&3); inverse applied on GLOBAL source (rule 21; == R8).
  const int srow = tid >> 2;
  const int csrc16 = ((tid & 3) ^ ((tid >> 3) & 3)) * 16;
  long long ra0 = brow + srow;        if (ra0 > N_PAD - 1) ra0 = N_PAD - 1;
  long long ra1 = brow + 128 + srow;  if (ra1 > N_PAD - 1) ra1 = N_PAD - 1;
  StageSrc8 s;
  s.a0 = A + ra0 * DD + csrc16;
  s.a1 = A + ra1 * DD + csrc16;
  s.b0 = B + (bcol + srow) * DD + csrc16;
  s.b1 = B + (bcol + 128 + srow) * DD + csrc16;

  const int rA = wr * 128 + (lane & 15);
  const int rB = wc * 64 + (lane & 15);
  const int qa = lane >> 4;                    // lane's K-group (superslot)
  const int sa = ((lane & 15) >> 1) & 3;       // row swizzle key (same A/B)
  const int offs = ((qa ^ sa) << 4);           // one b128 covers both kk

  f32x4 acc[8][4];
  f32x4 zero = {0.f, 0.f, 0.f, 0.f};
  #pragma unroll
  for (int m = 0; m < 8; ++m)
    #pragma unroll
    for (int n = 0; n < 4; ++n) acc[m][n] = zero;

  gemm_core256_fp8(s, As, Bs, wid, rA, rB, offs, acc);

  const float LN2 = 0.69314718055994530942f;
  float sAll = 0.f, sPos = 0.f, sDiag = 0.f;
  #pragma unroll
  for (int m = 0; m < 8; ++m) {
    #pragma unroll
    for (int j = 0; j < 4; ++j) {
      const int lr = wr * 128 + m * 16 + (lane >> 4) * 4 + j;
      const long long rowg = brow + lr;
      if (rowg < N_PAD) {
        const int bg = sbatch[lr];
        #pragma unroll
        for (int n = 0; n < 4; ++n) {
          const int col = (int)bcol + wc * 64 + n * 16 + (lane & 15);
          float v = acc[m][n][j];
          float t = __expf(-fabsf(v));
          float spn = fmaxf(-v, 0.f) + __logf(1.0f + t);   // softplus(-v)
          sAll += spn + v;
          if (col == bg) {
            sPos += LN2 - spn;
            sDiag += spn + v;
          }
        }
      }
    }
  }
  #pragma unroll
  for (int off = 32; off > 0; off >>= 1) {
    sAll  += __shfl_down(sAll, off);
    sPos  += __shfl_down(sPos, off);
    sDiag += __shfl_down(sDiag, off);
  }
  if (lane == 0) { sred[wid] = sPos; sred[8 + wid] = sAll; sred[16 + wid] = sDiag; }
  __syncthreads();
  if (tid == 0) {
    float p = 0.f, a = 0.f, d = 0.f;
    #pragma unroll
    for (int w = 0; w < 8; ++w) { p += sred[w]; a += sred[8 + w]; d += sred[16 + w]; }
    atomicAdd(accum,     (double)p);
    atomicAdd(accum + 1, (double)a);
    atomicAdd(accum + 2, (double)d);
  }
}

__global__ void finalize_kernel(const double* __restrict__ accum,
                                float* __restrict__ out) {
  if (threadIdx.x == 0 && blockIdx.x == 0) {
    const double LN2 = 0.6931471805599453094172321;
    double posSum = accum[0];
    double negSum = (accum[1] - accum[2])
                  - ((double)N_PAD * N_GRAPH - (double)N_NODE) * LN2;
    double Epos = posSum / (double)N_NODE;
    double Eneg = negSum / ((double)N_NODE * (double)(N_GRAPH - 1));
    out[0] = (float)(Eneg - Epos);
  }
}

// ---- launch -----------------------------------------------------------------

extern "C" void kernel_launch(void* const* d_in, const int* in_sizes, int n_in,
                              void* d_out, int out_size, void* d_ws, size_t ws_size,
                              hipStream_t stream) {
  const float* node  = (const float*)d_in[0];
  const float* graph = (const float*)d_in[1];
  const int*   batch = (const int*)d_in[2];
  const float* lw0 = (const float*)d_in[3];
  const float* lb0 = (const float*)d_in[4];
  const float* lw1 = (const float*)d_in[5];
  const float* lb1 = (const float*)d_in[6];
  const float* lw2 = (const float*)d_in[7];
  const float* lb2 = (const float*)d_in[8];
  const float* lws = (const float*)d_in[9];
  const float* lbs = (const float*)d_in[10];
  const float* gw0 = (const float*)d_in[11];
  const float* gb0 = (const float*)d_in[12];
  const float* gw1 = (const float*)d_in[13];
  const float* gb1 = (const float*)d_in[14];
  const float* gw2 = (const float*)d_in[15];
  const float* gb2 = (const float*)d_in[16];
  const float* gws = (const float*)d_in[17];
  const float* gbs = (const float*)d_in[18];

  // workspace layout (identical to R2-R9); l_enc/g_enc fp8 overlay H1/GH1
  char* ws = (char*)d_ws;
  double*         accum = (double*)ws;                          // 24 B
  unsigned short* WB  = (unsigned short*)(ws + 256);            // 8 x 512x512 bf16
  unsigned short* XB  = (unsigned short*)(ws + 4194560LL);      // [N_PAD,512] bf16
  unsigned short* H1  = (unsigned short*)(ws + 55443712LL);     // h1 bf16; later l_enc fp8
  unsigned short* H2  = (unsigned short*)(ws + 106692864LL);
  unsigned short* GXB = (unsigned short*)(ws + 157942016LL);
  unsigned short* GH1 = (unsigned short*)(ws + 158990592LL);    // gh1 bf16; later g_enc fp8
  unsigned short* GH2 = (unsigned short*)(ws + 160039168LL);
  if (ws_size < 161087744ULL) return;

  hipMemsetAsync(accum, 0, 32, stream);

  WPtrs wp;
  wp.p[0] = lw0; wp.p[1] = lw1; wp.p[2] = lw2; wp.p[3] = lws;
  wp.p[4] = gw0; wp.p[5] = gw1; wp.p[6] = gw2; wp.p[7] = gws;
  cast_w_kernel<<<1024, 256, 0, stream>>>(wp, WB);
  cast_pad_kernel<<<12512, 256, 0, stream>>>(node, XB, N_NODE, N_PAD);
  cast_pad_kernel<<<256, 256, 0, stream>>>(graph, GXB, N_GRAPH, N_GRAPH);

  // ---- ff chain: 128² bf16 kernels, combined l+g grid ----
  dim3 blk256(256);
  const int nwgL = 4 * 391;
  const int nwgG = 4 * 8;
  dim3 gff(nwgL + nwgG);

  gemm_ff_kernel<0><<<gff, blk256, 0, stream>>>(
      XB, WB + 0 * 262144, lb0, H1, nullptr, nullptr, nullptr, nwgL,
      GXB, WB + 4 * 262144, gb0, GH1, nullptr, nullptr, nullptr);
  gemm_ff_kernel<0><<<gff, blk256, 0, stream>>>(
      H1, WB + 1 * 262144, lb1, H2, nullptr, nullptr, nullptr, nwgL,
      GH1, WB + 5 * 262144, gb1, GH2, nullptr, nullptr, nullptr);
  // DUAL: reads H2+XB (l) / GH2+GXB (g), writes K-permuted fp8 into H1/GH1
  gemm_ff_kernel<1><<<gff, blk256, 0, stream>>>(
      H2, WB + 2 * 262144, lb2, H1, XB, WB + 3 * 262144, lbs, nwgL,
      GH2, WB + 6 * 262144, gb2, GH1, GXB, WB + 7 * 262144, gbs);

  zeropad8_kernel<<<6, 256, 0, stream>>>((unsigned char*)H1);

  // ---- jsd: 256² fp8 single-tile kernel, b128 permuted reads ----
  dim3 blk512(512);
  dim3 gr(196 * 4);                   // 784 blocks
  gemm_jsd256<<<gr, blk512, 0, stream>>>(
      (const unsigned char*)H1, (const unsigned char*)GH1, batch, accum);
  finalize_kernel<<<1, 64, 0, stream>>>(accum, (float*)d_out);
}

// Round 12
// 262.745 us; speedup vs baseline: 1.3028x; 1.1202x over previous
//
#include <hip/hip_runtime.h>
#include <hip/hip_bf16.h>

#define N_NODE  50000
#define N_PAD   50048   // 391 * 128
#define N_GRAPH 1024
#define DD      512
// fp8 cores: 64-byte K-step, K=512 -> 8 steps
#define NK8     8

typedef __attribute__((ext_vector_type(4))) float f32x4;
typedef __attribute__((ext_vector_type(2))) long long ll2;

// fp32 -> fp8 e4m3fn, RNE, BRANCHLESS (R8 lesson: early-returns diverge)
__device__ __forceinline__ unsigned char f2fp8(float f) {
  unsigned int u = __builtin_bit_cast(unsigned int, f);
  unsigned int sg = (u >> 24) & 0x80u;
  float a = __builtin_bit_cast(float, u & 0x7fffffffu);
  a = fminf(a, 448.0f);
  unsigned int r = __builtin_bit_cast(unsigned int, a);
  unsigned int rn = r + 0x7ffffu + ((r >> 20) & 1u);   // RNE at mantissa bit 20
  int codeN = (int)(rn >> 20) - (120 << 3);            // ((e+127)<<3|m3) - 960
  int codeS = (int)rintf(a * 512.0f);                  // subnormal grid 2^-9
  int code = (a >= 0.015625f) ? codeN : codeS;
  code = code > 0x7E ? 0x7E : code;
  return (unsigned char)(sg | (unsigned int)code);
}

// K-permutation (R10-verified): within each 64-col group, phys position
// p = ((k>>3)&3)<<4 | (k>>5)<<3 | (k&7). A lane's two MFMA kk-operands are
// then 16 contiguous bytes (one ds_read_b128). Upper bits pass through.
__device__ __forceinline__ long long permute_col(long long c) {
  int o = (int)c & 63;
  int p = (((o >> 3) & 3) << 4) | ((o >> 5) << 3) | (o & 7);
  return (c & ~63LL) | p;
}

__device__ __forceinline__ void gload16(const void* g, void* l) {
  __builtin_amdgcn_global_load_lds(
      (const __attribute__((address_space(1))) unsigned int*)g,
      (__attribute__((address_space(3))) unsigned int*)l, 16, 0, 0);
}

// T1: bijective XCD-chunk remap (m204 variant)
__device__ __forceinline__ int xcd_remap(int bid, int nwg) {
  int xcd = bid & 7;
  int local = bid >> 3;
  int q = nwg >> 3, r = nwg & 7;
  int base = (xcd < r) ? xcd * (q + 1) : r * (q + 1) + (xcd - r) * q;
  return base + local;
}

// ---- fp8 cast kernels (write K-permuted) ------------------------------------

__global__ void cast_pad8_kernel(const float* __restrict__ src,
                                 unsigned char* __restrict__ dst,
                                 int srcRows, int dstRows) {
  long long base = ((long long)blockIdx.x * blockDim.x + threadIdx.x) * 8;
  if (base >= (long long)dstRows * DD) return;
  int row = (int)(base >> 9);
  unsigned long long pk = 0ULL;
  if (row < srcRows) {
    float4 x0 = reinterpret_cast<const float4*>(src + base)[0];
    float4 x1 = reinterpret_cast<const float4*>(src + base)[1];
    pk  = (unsigned long long)f2fp8(x0.x);
    pk |= (unsigned long long)f2fp8(x0.y) << 8;
    pk |= (unsigned long long)f2fp8(x0.z) << 16;
    pk |= (unsigned long long)f2fp8(x0.w) << 24;
    pk |= (unsigned long long)f2fp8(x1.x) << 32;
    pk |= (unsigned long long)f2fp8(x1.y) << 40;
    pk |= (unsigned long long)f2fp8(x1.z) << 48;
    pk |= (unsigned long long)f2fp8(x1.w) << 56;
  }
  *reinterpret_cast<unsigned long long*>(dst + permute_col(base)) = pk;
}

struct WPtrs { const float* p[8]; };

__global__ void cast_w8_kernel(WPtrs ps, unsigned char* __restrict__ dst) {
  long long base = ((long long)blockIdx.x * blockDim.x + threadIdx.x) * 8;
  int mat = (int)(base >> 18);           // 512*512 = 2^18 elems per matrix
  long long off = base & 262143LL;
  const float* s = ps.p[mat] + off;
  float4 x0 = reinterpret_cast<const float4*>(s)[0];
  float4 x1 = reinterpret_cast<const float4*>(s)[1];
  unsigned long long pk;
  pk  = (unsigned long long)f2fp8(x0.x);
  pk |= (unsigned long long)f2fp8(x0.y) << 8;
  pk |= (unsigned long long)f2fp8(x0.z) << 16;
  pk |= (unsigned long long)f2fp8(x0.w) << 24;
  pk |= (unsigned long long)f2fp8(x1.x) << 32;
  pk |= (unsigned long long)f2fp8(x1.y) << 40;
  pk |= (unsigned long long)f2fp8(x1.z) << 48;
  pk |= (unsigned long long)f2fp8(x1.w) << 56;
  *reinterpret_cast<unsigned long long*>(
      dst + (long long)mat * 262144 + permute_col(off)) = pk;
}

__global__ void zeropad8_kernel(unsigned char* __restrict__ H) {
  long long i = (long long)blockIdx.x * blockDim.x + threadIdx.x;
  long long base = (long long)N_NODE * DD + i * 16;
  if (base < (long long)N_PAD * DD) {
    int4 z = {0, 0, 0, 0};
    *reinterpret_cast<int4*>(H + base) = z;
  }
}

// ============================================================================
// 128x128 fp8 core: 4-slot circular LDS, counted vmcnt (R8/R10 skeleton at
// 128² geometry). LDS/side = 4 x [128 rows][64 B] = 32 KB; both sides 64 KB
// -> 2 blocks/CU at 256 thr. Stage = 4 gloads/thread (A-rows r0,r0+64; B same)
// -> identical vmcnt constants to R10: steady 8, tail 4, 0.
// Staging swizzle (R10-verified): phys superslot p=tid&3 of row r holds
// logical p ^ ((r>>1)&3); inverse applied on GLOBAL source (rule 21).
// Read: one ds_read_b128 per fragment at offs=(qa^sa)<<4 (0 conflicts, R10).
// ============================================================================

__device__ __forceinline__ void ff_stage(const unsigned char* aptr,
                                         const unsigned char* bptr, int kbyte,
                                         unsigned char* sA, unsigned char* sB,
                                         int wid) {
  unsigned char* dA = sA + wid * 1024;   // wave-uniform; HW adds lane*16B
  unsigned char* dB = sB + wid * 1024;
  gload16(aptr + kbyte, dA);
  gload16(aptr + 64LL * DD + kbyte, dA + 4096);
  gload16(bptr + kbyte, dB);
  gload16(bptr + 64LL * DD + kbyte, dB + 4096);
}

__device__ __forceinline__ void gemm_core128_fp8(
    const unsigned char* aptr, const unsigned char* bptr,
    unsigned char* As, unsigned char* Bs,
    int wid, int rA, int rB, int offs, f32x4 acc[4][4]) {
  ff_stage(aptr, bptr, 0, As, Bs, wid);
  ff_stage(aptr, bptr, 64, As + 8192, Bs + 8192, wid);
  ff_stage(aptr, bptr, 128, As + 16384, Bs + 16384, wid);
  #pragma unroll
  for (int t = 0; t < NK8; ++t) {
    __builtin_amdgcn_sched_barrier(0);
    if (t < NK8 - 2)       asm volatile("s_waitcnt vmcnt(8)" ::: "memory");
    else if (t == NK8 - 2) asm volatile("s_waitcnt vmcnt(4)" ::: "memory");
    else                   asm volatile("s_waitcnt vmcnt(0)" ::: "memory");
    __builtin_amdgcn_s_barrier();
    __builtin_amdgcn_sched_barrier(0);
    if (t + 3 < NK8)
      ff_stage(aptr, bptr, (t + 3) * 64, As + ((t + 3) & 3) * 8192,
               Bs + ((t + 3) & 3) * 8192, wid);
    const unsigned char* as = As + (t & 3) * 8192;
    const unsigned char* bs = Bs + (t & 3) * 8192;
    ll2 a[4], b[4];
    #pragma unroll
    for (int m = 0; m < 4; ++m)
      a[m] = *reinterpret_cast<const ll2*>(as + (rA + m * 16) * 64 + offs);
    #pragma unroll
    for (int n = 0; n < 4; ++n)
      b[n] = *reinterpret_cast<const ll2*>(bs + (rB + n * 16) * 64 + offs);
    __builtin_amdgcn_s_setprio(1);
    #pragma unroll
    for (int m = 0; m < 4; ++m)
      #pragma unroll
      for (int n = 0; n < 4; ++n)
        acc[m][n] = __builtin_amdgcn_mfma_f32_16x16x32_fp8_fp8(a[m][0], b[n][0], acc[m][n], 0, 0, 0);
    #pragma unroll
    for (int m = 0; m < 4; ++m)
      #pragma unroll
      for (int n = 0; n < 4; ++n)
        acc[m][n] = __builtin_amdgcn_mfma_f32_16x16x32_fp8_fp8(a[m][1], b[n][1], acc[m][n], 0, 0, 0);
    __builtin_amdgcn_s_setprio(0);
  }
}

// ---- FF GEMM (fp8 in, fp8 out K-permuted): C = relu(A@W^T + b)
//      DUAL: C = relu(A@W^T+b) + A2@W2^T + b2

template <int DUAL>
__global__ __launch_bounds__(256, 2) void gemm_ff8(
    const unsigned char* __restrict__ Al, const unsigned char* __restrict__ Wl,
    const float* __restrict__ biasl, unsigned char* __restrict__ Cl,
    const unsigned char* __restrict__ A2l, const unsigned char* __restrict__ W2l,
    const float* __restrict__ bias2l, int nwgL,
    const unsigned char* __restrict__ Ag, const unsigned char* __restrict__ Wg,
    const float* __restrict__ biasg, unsigned char* __restrict__ Cg,
    const unsigned char* __restrict__ A2g, const unsigned char* __restrict__ W2g,
    const float* __restrict__ bias2g) {
  __shared__ unsigned char As[4 * 8192];
  __shared__ unsigned char Bs[4 * 8192];
  const int tid = threadIdx.x;
  const int lane = tid & 63, wid = tid >> 6;
  const int wr = wid >> 1, wc = wid & 1;

  int tile = xcd_remap(blockIdx.x, gridDim.x);
  const unsigned char *A, *W, *A2, *W2;
  const float *bias, *bias2;
  unsigned char* C;
  if (tile < nwgL) {
    A = Al; W = Wl; bias = biasl; C = Cl; A2 = A2l; W2 = W2l; bias2 = bias2l;
  } else {
    tile -= nwgL;
    A = Ag; W = Wg; bias = biasg; C = Cg; A2 = A2g; W2 = W2g; bias2 = bias2g;
  }
  const long long brow = (long long)(tile >> 2) * 128;
  const long long bcol = (long long)(tile & 3) * 128;

  // staging geometry: r0 = wave*16 + (lane>>2); phys superslot = tid&3
  const int r0 = (tid >> 6) * 16 + ((tid & 63) >> 2);
  const int csrc = (((tid & 3) ^ ((r0 >> 1) & 3))) * 16;  // key same for r0+64
  const unsigned char* aptr = A + (brow + r0) * DD + csrc;
  const unsigned char* bptr = W + (bcol + r0) * DD + csrc;

  const int rA = wr * 64 + (lane & 15);
  const int rB = wc * 64 + (lane & 15);
  const int offs = (((lane >> 4) ^ (((lane & 15) >> 1) & 3)) << 4);

  f32x4 acc[4][4];
  f32x4 zero = {0.f, 0.f, 0.f, 0.f};
  #pragma unroll
  for (int m = 0; m < 4; ++m)
    #pragma unroll
    for (int n = 0; n < 4; ++n) acc[m][n] = zero;

  gemm_core128_fp8(aptr, bptr, As, Bs, wid, rA, rB, offs, acc);

  float bv[4];
  #pragma unroll
  for (int n = 0; n < 4; ++n) bv[n] = bias[bcol + wc * 64 + n * 16 + (lane & 15)];

  if constexpr (DUAL) {
    float r[4][4][4];
    #pragma unroll
    for (int m = 0; m < 4; ++m)
      #pragma unroll
      for (int n = 0; n < 4; ++n)
        #pragma unroll
        for (int j = 0; j < 4; ++j)
          r[m][n][j] = fmaxf(acc[m][n][j] + bv[n], 0.f);
    #pragma unroll
    for (int m = 0; m < 4; ++m)
      #pragma unroll
      for (int n = 0; n < 4; ++n) acc[m][n] = zero;

    const unsigned char* aptr2 = A2 + (brow + r0) * DD + csrc;
    const unsigned char* bptr2 = W2 + (bcol + r0) * DD + csrc;
    gemm_core128_fp8(aptr2, bptr2, As, Bs, wid, rA, rB, offs, acc);

    float b2[4];
    #pragma unroll
    for (int n = 0; n < 4; ++n) b2[n] = bias2[bcol + wc * 64 + n * 16 + (lane & 15)];

    #pragma unroll
    for (int m = 0; m < 4; ++m) {
      const long long row = brow + wr * 64 + m * 16 + (lane >> 4) * 4;
      #pragma unroll
      for (int j = 0; j < 4; ++j)
        #pragma unroll
        for (int n = 0; n < 4; ++n) {
          const long long col = bcol + wc * 64 + n * 16 + (lane & 15);
          float v = r[m][n][j] + acc[m][n][j] + b2[n];
          C[(row + j) * DD + permute_col(col)] = f2fp8(v);
        }
    }
  } else {
    #pragma unroll
    for (int m = 0; m < 4; ++m) {
      const long long row = brow + wr * 64 + m * 16 + (lane >> 4) * 4;
      #pragma unroll
      for (int j = 0; j < 4; ++j)
        #pragma unroll
        for (int n = 0; n < 4; ++n) {
          const long long col = bcol + wc * 64 + n * 16 + (lane & 15);
          float v = fmaxf(acc[m][n][j] + bv[n], 0.f);
          C[(row + j) * DD + permute_col(col)] = f2fp8(v);
        }
    }
  }
}

// ============================================================================
// jsd side: R10's 256x256 fp8 4-slot counted-vmcnt core, b128 permuted reads.
// BYTE-IDENTICAL to R10 (112 µs, 0 conflicts, no spill).
// ============================================================================

struct StageSrc8 { const unsigned char *a0, *a1, *b0, *b1; };

__device__ __forceinline__ void issue_stage8(const StageSrc8& s, int kbyte,
                                             unsigned char* sA, unsigned char* sB,
                                             int wid) {
  unsigned char* dA = sA + wid * 1024;   // wave-uniform; HW adds lane*16B
  unsigned char* dB = sB + wid * 1024;
  gload16(s.a0 + kbyte, dA);
  gload16(s.a1 + kbyte, dA + 8192);
  gload16(s.b0 + kbyte, dB);
  gload16(s.b1 + kbyte, dB + 8192);
}

__device__ __forceinline__ void gemm_core256_fp8(
    const StageSrc8& s, unsigned char* As, unsigned char* Bs,
    int wid, int rA, int rB, int offs, f32x4 acc[8][4]) {
  issue_stage8(s, 0, As, Bs, wid);
  issue_stage8(s, 64, As + 16384, Bs + 16384, wid);
  issue_stage8(s, 128, As + 32768, Bs + 32768, wid);
  #pragma unroll
  for (int t = 0; t < NK8; ++t) {
    __builtin_amdgcn_sched_barrier(0);
    if (t < NK8 - 2)       asm volatile("s_waitcnt vmcnt(8)" ::: "memory");
    else if (t == NK8 - 2) asm volatile("s_waitcnt vmcnt(4)" ::: "memory");
    else                   asm volatile("s_waitcnt vmcnt(0)" ::: "memory");
    __builtin_amdgcn_s_barrier();
    __builtin_amdgcn_sched_barrier(0);
    if (t + 3 < NK8)
      issue_stage8(s, (t + 3) * 64, As + ((t + 3) & 3) * 16384,
                   Bs + ((t + 3) & 3) * 16384, wid);
    const unsigned char* as = As + (t & 3) * 16384;
    const unsigned char* bs = Bs + (t & 3) * 16384;
    ll2 a[8], b[4];
    #pragma unroll
    for (int m = 0; m < 8; ++m)
      a[m] = *reinterpret_cast<const ll2*>(as + (rA + m * 16) * 64 + offs);
    #pragma unroll
    for (int n = 0; n < 4; ++n)
      b[n] = *reinterpret_cast<const ll2*>(bs + (rB + n * 16) * 64 + offs);
    __builtin_amdgcn_s_setprio(1);
    #pragma unroll
    for (int m = 0; m < 8; ++m)
      #pragma unroll
      for (int n = 0; n < 4; ++n)
        acc[m][n] = __builtin_amdgcn_mfma_f32_16x16x32_fp8_fp8(a[m][0], b[n][0], acc[m][n], 0, 0, 0);
    #pragma unroll
    for (int m = 0; m < 8; ++m)
      #pragma unroll
      for (int n = 0; n < 4; ++n)
        acc[m][n] = __builtin_amdgcn_mfma_f32_16x16x32_fp8_fp8(a[m][1], b[n][1], acc[m][n], 0, 0, 0);
    __builtin_amdgcn_s_setprio(0);
  }
}

// accum[0] = sum_diag (LN2 - softplus(-v))
// accum[1] = sum_all  (softplus(-v) + v)   (rows < N_PAD; zero rows -> ln2)
// accum[2] = sum_diag (softplus(-v) + v)

__global__ __launch_bounds__(512, 2) void gemm_jsd256(
    const unsigned char* __restrict__ A, const unsigned char* __restrict__ B,
    const int* __restrict__ batch, double* __restrict__ accum) {
  __shared__ unsigned char As[4 * 16384];
  __shared__ unsigned char Bs[4 * 16384];
  __shared__ int sbatch[256];
  __shared__ float sred[24];
  const int tid = threadIdx.x;
  const int lane = tid & 63, wid = tid >> 6;
  const int wr = wid >> 2, wc = wid & 3;

  const int tile = xcd_remap(blockIdx.x, gridDim.x);
  const long long brow = (long long)(tile >> 2) * 256;
  const long long bcol = (long long)(tile & 3) * 256;

  if (tid < 256) {
    long long gr = brow + tid;
    sbatch[tid] = (gr < N_NODE) ? batch[gr] : -1;
  }

  const int srow = tid >> 2;
  const int csrc16 = ((tid & 3) ^ ((tid >> 3) & 3)) * 16;
  long long ra0 = brow + srow;        if (ra0 > N_PAD - 1) ra0 = N_PAD - 1;
  long long ra1 = brow + 128 + srow;  if (ra1 > N_PAD - 1) ra1 = N_PAD - 1;
  StageSrc8 s;
  s.a0 = A + ra0 * DD + csrc16;
  s.a1 = A + ra1 * DD + csrc16;
  s.b0 = B + (bcol + srow) * DD + csrc16;
  s.b1 = B + (bcol + 128 + srow) * DD + csrc16;

  const int rA = wr * 128 + (lane & 15);
  const int rB = wc * 64 + (lane & 15);
  const int qa = lane >> 4;
  const int sa = ((lane & 15) >> 1) & 3;
  const int offs = ((qa ^ sa) << 4);

  f32x4 acc[8][4];
  f32x4 zero = {0.f, 0.f, 0.f, 0.f};
  #pragma unroll
  for (int m = 0; m < 8; ++m)
    #pragma unroll
    for (int n = 0; n < 4; ++n) acc[m][n] = zero;

  gemm_core256_fp8(s, As, Bs, wid, rA, rB, offs, acc);

  const float LN2 = 0.69314718055994530942f;
  float sAll = 0.f, sPos = 0.f, sDiag = 0.f;
  #pragma unroll
  for (int m = 0; m < 8; ++m) {
    #pragma unroll
    for (int j = 0; j < 4; ++j) {
      const int lr = wr * 128 + m * 16 + (lane >> 4) * 4 + j;
      const long long rowg = brow + lr;
      if (rowg < N_PAD) {
        const int bg = sbatch[lr];
        #pragma unroll
        for (int n = 0; n < 4; ++n) {
          const int col = (int)bcol + wc * 64 + n * 16 + (lane & 15);
          float v = acc[m][n][j];
          float t = __expf(-fabsf(v));
          float spn = fmaxf(-v, 0.f) + __logf(1.0f + t);   // softplus(-v)
          sAll += spn + v;
          if (col == bg) {
            sPos += LN2 - spn;
            sDiag += spn + v;
          }
        }
      }
    }
  }
  #pragma unroll
  for (int off = 32; off > 0; off >>= 1) {
    sAll  += __shfl_down(sAll, off);
    sPos  += __shfl_down(sPos, off);
    sDiag += __shfl_down(sDiag, off);
  }
  if (lane == 0) { sred[wid] = sPos; sred[8 + wid] = sAll; sred[16 + wid] = sDiag; }
  __syncthreads();
  if (tid == 0) {
    float p = 0.f, a = 0.f, d = 0.f;
    #pragma unroll
    for (int w = 0; w < 8; ++w) { p += sred[w]; a += sred[8 + w]; d += sred[16 + w]; }
    atomicAdd(accum,     (double)p);
    atomicAdd(accum + 1, (double)a);
    atomicAdd(accum + 2, (double)d);
  }
}

__global__ void finalize_kernel(const double* __restrict__ accum,
                                float* __restrict__ out) {
  if (threadIdx.x == 0 && blockIdx.x == 0) {
    const double LN2 = 0.6931471805599453094172321;
    double posSum = accum[0];
    double negSum = (accum[1] - accum[2])
                  - ((double)N_PAD * N_GRAPH - (double)N_NODE) * LN2;
    double Epos = posSum / (double)N_NODE;
    double Eneg = negSum / ((double)N_NODE * (double)(N_GRAPH - 1));
    out[0] = (float)(Eneg - Epos);
  }
}

// ---- launch -----------------------------------------------------------------

extern "C" void kernel_launch(void* const* d_in, const int* in_sizes, int n_in,
                              void* d_out, int out_size, void* d_ws, size_t ws_size,
                              hipStream_t stream) {
  const float* node  = (const float*)d_in[0];
  const float* graph = (const float*)d_in[1];
  const int*   batch = (const int*)d_in[2];
  const float* lw0 = (const float*)d_in[3];
  const float* lb0 = (const float*)d_in[4];
  const float* lw1 = (const float*)d_in[5];
  const float* lb1 = (const float*)d_in[6];
  const float* lw2 = (const float*)d_in[7];
  const float* lb2 = (const float*)d_in[8];
  const float* lws = (const float*)d_in[9];
  const float* lbs = (const float*)d_in[10];
  const float* gw0 = (const float*)d_in[11];
  const float* gb0 = (const float*)d_in[12];
  const float* gw1 = (const float*)d_in[13];
  const float* gb1 = (const float*)d_in[14];
  const float* gw2 = (const float*)d_in[15];
  const float* gb2 = (const float*)d_in[16];
  const float* gws = (const float*)d_in[17];
  const float* gbs = (const float*)d_in[18];

  // workspace layout (same offsets as R2-R10; all regions now fp8 = smaller)
  char* ws = (char*)d_ws;
  double*        accum = (double*)ws;                        // 24 B
  unsigned char* WB8  = (unsigned char*)(ws + 256);          // 8 x 256KB fp8 perm
  unsigned char* XB8  = (unsigned char*)(ws + 4194560LL);    // [N_PAD,512] fp8 perm
  unsigned char* H1_8 = (unsigned char*)(ws + 55443712LL);   // h1; later l_enc
  unsigned char* H2_8 = (unsigned char*)(ws + 106692864LL);
  unsigned char* GXB8 = (unsigned char*)(ws + 157942016LL);
  unsigned char* GH18 = (unsigned char*)(ws + 158990592LL);  // gh1; later g_enc
  unsigned char* GH28 = (unsigned char*)(ws + 160039168LL);
  if (ws_size < 161087744ULL) return;

  hipMemsetAsync(accum, 0, 32, stream);

  WPtrs wp;
  wp.p[0] = lw0; wp.p[1] = lw1; wp.p[2] = lw2; wp.p[3] = lws;
  wp.p[4] = gw0; wp.p[5] = gw1; wp.p[6] = gw2; wp.p[7] = gws;
  cast_w8_kernel<<<1024, 256, 0, stream>>>(wp, WB8);
  cast_pad8_kernel<<<12512, 256, 0, stream>>>(node, XB8, N_NODE, N_PAD);
  cast_pad8_kernel<<<256, 256, 0, stream>>>(graph, GXB8, N_GRAPH, N_GRAPH);

  // ---- ff chain: 128² fp8 counted-vmcnt kernels, combined l+g grid ----
  dim3 blk256(256);
  const int nwgL = 4 * 391;
  const int nwgG = 4 * 8;
  dim3 gff(nwgL + nwgG);

  gemm_ff8<0><<<gff, blk256, 0, stream>>>(
      XB8, WB8 + 0 * 262144, lb0, H1_8, nullptr, nullptr, nullptr, nwgL,
      GXB8, WB8 + 4 * 262144, gb0, GH18, nullptr, nullptr, nullptr);
  gemm_ff8<0><<<gff, blk256, 0, stream>>>(
      H1_8, WB8 + 1 * 262144, lb1, H2_8, nullptr, nullptr, nullptr, nwgL,
      GH18, WB8 + 5 * 262144, gb1, GH28, nullptr, nullptr, nullptr);
  // DUAL: reads H2+XB (l) / GH2+GXB (g), writes l_enc/g_enc into H1/GH1
  gemm_ff8<1><<<gff, blk256, 0, stream>>>(
      H2_8, WB8 + 2 * 262144, lb2, H1_8, XB8, WB8 + 3 * 262144, lbs, nwgL,
      GH28, WB8 + 6 * 262144, gb2, GH18, GXB8, WB8 + 7 * 262144, gbs);

  zeropad8_kernel<<<6, 256, 0, stream>>>(H1_8);

  // ---- jsd: 256² fp8 single-tile kernel (R10 verbatim) ----
  dim3 blk512(512);
  dim3 gr(196 * 4);                   // 784 blocks
  gemm_jsd256<<<gr, blk512, 0, stream>>>(H1_8, GH18, batch, accum);
  finalize_kernel<<<1, 64, 0, stream>>>(accum, (float*)d_out);
}